// Round 8
// baseline (128.947 us; speedup 1.0000x reference)
//
#include <hip/hip_runtime.h>
#include <hip/hip_bf16.h>

typedef __attribute__((ext_vector_type(8))) short short8;
typedef __attribute__((ext_vector_type(4))) float floatx4;
typedef __attribute__((ext_vector_type(4))) unsigned int uintx4;
#define BF16 __hip_bfloat16

__device__ __forceinline__ unsigned short f2bf(float f) {
  unsigned int u = __builtin_bit_cast(unsigned int, f);
  unsigned int r = (u + 0x7FFFu + ((u >> 16) & 1u)) >> 16;
  return (unsigned short)r;
}

__device__ __forceinline__ unsigned int cvt_pk_bf16(float lo, float hi) {
  unsigned int r;
  asm("v_cvt_pk_bf16_f32 %0, %1, %2" : "=v"(r) : "v"(lo), "v"(hi));
  return r;
}

__device__ __forceinline__ void gload_lds16(const void* g, void* l) {
  __builtin_amdgcn_global_load_lds(
      (const __attribute__((address_space(1))) unsigned int*)g,
      (__attribute__((address_space(3))) unsigned int*)l, 16, 0, 0);
}

// ---------- elementwise f32 -> bf16 ----------
__global__ __launch_bounds__(256)
void cvt_bf16(const float* __restrict__ in, unsigned short* __restrict__ out, int n) {
  int i = (blockIdx.x * 256 + threadIdx.x) * 8;
  if (i >= n) return;
  float4 a = *(const float4*)(in + i);
  float4 b = *(const float4*)(in + i + 4);
  short8 v;
  v[0] = (short)f2bf(a.x); v[1] = (short)f2bf(a.y);
  v[2] = (short)f2bf(a.z); v[3] = (short)f2bf(a.w);
  v[4] = (short)f2bf(b.x); v[5] = (short)f2bf(b.y);
  v[6] = (short)f2bf(b.z); v[7] = (short)f2bf(b.w);
  *(short8*)(out + i) = v;
}

// ---------- transpose+convert: in[K][N] f32 -> out[N][K] bf16 ----------
__global__ __launch_bounds__(256)
void transpose_cvt(const float* __restrict__ in, unsigned short* __restrict__ out,
                   int K, int N) {
  __shared__ float tile[64][65];
  const int nb = N >> 6;
  const int tn = blockIdx.x % nb, tk = blockIdx.x / nb;
  const int n0 = tn << 6, k0 = tk << 6;
  const int tid = threadIdx.x;
#pragma unroll
  for (int c = 0; c < 4; ++c) {
    int t = tid + c * 256;            // [0,1024): 64 rows x 16 float4
    int r = t >> 4, col = (t & 15) << 2;
    float4 v = *(const float4*)(in + (size_t)(k0 + r) * N + n0 + col);
    tile[r][col] = v.x; tile[r][col + 1] = v.y;
    tile[r][col + 2] = v.z; tile[r][col + 3] = v.w;
  }
  __syncthreads();
#pragma unroll
  for (int c = 0; c < 2; ++c) {
    int t = tid + c * 256;            // [0,512): 64 n-rows x 8 short8
    int r = t >> 3, col = (t & 7) << 3;   // r = local n, col = local k
    short8 v;
#pragma unroll
    for (int j = 0; j < 8; ++j) v[j] = (short)f2bf(tile[col + j][r]);
    *(short8*)(out + (size_t)(n0 + r) * K + k0 + col) = v;
  }
}

// ---------- QKV GEMM: 256x192 tile, BK=64, SINGLE-buffered, 512 thr ----------
// R8: the kernel is staging-BANDWIDTH-bound (~15-16 B/cyc/CU on the
// global_load_lds path; proj@1blk == qkv@3blk per-block-iter, TLP ~ 0; every
// dbuf/phase variant DEGRADED B/cyc: R5 9.1, R6 ~5-11, R7 6.6 vs R4 15.0).
// So: keep the R4 simple stage->syncthreads->MFMA->syncthreads loop (best
// measured B/cyc) and cut staged bytes/FLOP 1.72x via 256x192 tile.
// Grid 16x16 = 256 = 1 block/CU. LDS 56KB. 8 waves (2Mx4N), acc 8x3.
// XCD swizzle: each XCD owns 2 bn columns (768KB B slice, L2-resident).
// Scatter epilogue: q,k -> [2][16][2048][64]; v -> [2][16][64][2048] bf16.
__global__ __launch_bounds__(512, 2)
void gemm_qkv(const BF16* __restrict__ A, const BF16* __restrict__ Bt,
              const float* __restrict__ bias, BF16* __restrict__ out,
              int M, int N, int K) {
  const int tid = threadIdx.x;
  const int w = tid >> 6, l = tid & 63;
  const int lr = l & 15, lg = l >> 4;
  const int bid = (int)blockIdx.x;
  const int bidp = (bid & 7) * 32 + (bid >> 3);   // XCD x -> bn {2x,2x+1}
  const int bm = bidp & 15, bn = bidp >> 4;
  const int row0 = bm << 8;          // 256 rows
  const int col0 = bn * 192;
  const int wm = w >> 2, wn = w & 3;
  const int r0 = wm << 7;            // wave row base (0/128)
  const int c0w = wn * 48;           // wave col base (0/48/96/144)

  __shared__ __align__(16) BF16 ldsA[256 * 64];   // 32 KB
  __shared__ __align__(16) BF16 ldsB[192 * 64];   // 24 KB

  floatx4 acc[8][3] = {};
  const int swzl = (lr & 7) << 3;

  for (int k0 = 0; k0 < K; k0 += 64) {
#pragma unroll
    for (int c = 0; c < 4; ++c) {      // A: 2048 chunks of 16B
      int t = tid + c * 512;
      int ar = t >> 3;
      int ch = (t & 7) ^ (ar & 7);
      gload_lds16(A + (size_t)(row0 + ar) * K + k0 + (ch << 3),
                  ldsA + w * 512 + c * 4096);
    }
#pragma unroll
    for (int c = 0; c < 3; ++c) {      // B: 1536 chunks of 16B
      int t = tid + c * 512;
      int br = t >> 3;
      int ch = (t & 7) ^ (br & 7);
      gload_lds16(Bt + (size_t)(col0 + br) * K + k0 + (ch << 3),
                  ldsB + w * 512 + c * 4096);
    }
    __syncthreads();
#pragma unroll
    for (int kk = 0; kk < 64; kk += 32) {
      short8 bf[3];
#pragma unroll
      for (int n = 0; n < 3; ++n)
        bf[n] = *(const short8*)(ldsB + (c0w + n * 16 + lr) * 64 + ((kk + lg * 8) ^ swzl));
#pragma unroll
      for (int m = 0; m < 8; ++m) {
        short8 af = *(const short8*)(ldsA + (r0 + m * 16 + lr) * 64 + ((kk + lg * 8) ^ swzl));
#pragma unroll
        for (int n = 0; n < 3; ++n)
          acc[m][n] = __builtin_amdgcn_mfma_f32_16x16x32_bf16(af, bf[n], acc[m][n], 0, 0, 0);
      }
    }
    __syncthreads();
  }

#pragma unroll
  for (int m = 0; m < 8; ++m)
#pragma unroll
    for (int n = 0; n < 3; ++n)
#pragma unroll
      for (int j = 0; j < 4; ++j) {
        int row = row0 + r0 + m * 16 + lg * 4 + j;   // m index (b*2048 + t)
        int col = col0 + c0w + n * 16 + lr;          // n index [0,3072)
        float v = acc[m][n][j] + bias[col];
        int s = col >> 10, cc = col & 1023;
        int hh = cc >> 6, dd = cc & 63;
        int bb = row >> 11, tt = row & 2047;
        size_t addr;
        if (s == 2)
          addr = (size_t)8388608 + (((size_t)bb * 16 + hh) * 64 + dd) * 2048 + tt;
        else
          addr = (size_t)s * 4194304 + (((size_t)bb * 16 + hh) * 2048 + tt) * 64 + dd;
        out[addr] = __float2bfloat16(v);
      }
}

// ---------- proj GEMM: C[M][N] = A[M][K] @ Bt[N][K]^T + bias, f32 out ----------
// R4-proven single-buffered BK=64 128x128 (16.0 B/cyc/CU - the measured
// optimum of the staging path; grid 256 = 1/CU).
__global__ __launch_bounds__(256, 2)
void gemm_proj(const BF16* __restrict__ A, const BF16* __restrict__ Bt,
               const float* __restrict__ bias, float* __restrict__ out,
               int M, int N, int K) {
  const int tid = threadIdx.x;
  const int w = tid >> 6, l = tid & 63;
  const int lr = l & 15, lg = l >> 4;
  const int nbx = N >> 7;
  const int bm = blockIdx.x / nbx, bn = blockIdx.x % nbx;
  const int row0 = bm << 7, col0 = bn << 7;
  const int wr = (w >> 1) << 6, wc = (w & 1) << 6;

  __shared__ __align__(16) BF16 ldsA[128 * 64];
  __shared__ __align__(16) BF16 ldsB[128 * 64];

  floatx4 acc[4][4] = {};
  const int swzl = (lr & 7) << 3;

  for (int k0 = 0; k0 < K; k0 += 64) {
#pragma unroll
    for (int c = 0; c < 4; ++c) {
      int t = w * 64 + l + c * 256;
      int ar = t >> 3;
      int ch = (t & 7) ^ (ar & 7);
      gload_lds16(A + (size_t)(row0 + ar) * K + k0 + (ch << 3),
                  ldsA + w * 512 + c * 2048);
      gload_lds16(Bt + (size_t)(col0 + ar) * K + k0 + (ch << 3),
                  ldsB + w * 512 + c * 2048);
    }
    __syncthreads();
#pragma unroll
    for (int kk = 0; kk < 64; kk += 32) {
      short8 af[4], bf[4];
#pragma unroll
      for (int m = 0; m < 4; ++m)
        af[m] = *(const short8*)(ldsA + (wr + m * 16 + lr) * 64 + ((kk + lg * 8) ^ swzl));
#pragma unroll
      for (int n = 0; n < 4; ++n)
        bf[n] = *(const short8*)(ldsB + (wc + n * 16 + lr) * 64 + ((kk + lg * 8) ^ swzl));
#pragma unroll
      for (int m = 0; m < 4; ++m)
#pragma unroll
        for (int n = 0; n < 4; ++n)
          acc[m][n] = __builtin_amdgcn_mfma_f32_16x16x32_bf16(af[m], bf[n], acc[m][n], 0, 0, 0);
    }
    __syncthreads();
  }

#pragma unroll
  for (int m = 0; m < 4; ++m)
#pragma unroll
    for (int n = 0; n < 4; ++n)
#pragma unroll
      for (int j = 0; j < 4; ++j) {
        int row = row0 + wr + m * 16 + lg * 4 + j;
        int col = col0 + wc + n * 16 + lr;
        out[(size_t)row * N + col] = acc[m][n][j] + bias[col];
      }
}

// ---------- causal flash attention, KV-half-split blocks ----------
// q: [2][16][2048][64], k: [2][16][2048][64], vt: [2][16][64][2048]
// 2048 blocks x 256 thr. Job = (bh, qt, par): even/odd KV tiles of one
// 64-row q-tile, size-descending dispatch. Static-max softmax -> additive
// partials; attn_merge sums halves and normalizes.
__global__ __launch_bounds__(256, 5)
void flash_attn(const BF16* __restrict__ qkv, float* __restrict__ PO,
                float* __restrict__ PL) {
  const int T = 2048;
  const int bid = blockIdx.x;
  const int J = bid >> 5;          // 0..63, size-descending (qt = 31 - J/2)
  const int bh = bid & 31;         // low 3 bits -> XCD; 4 heads per XCD L2
  const int qt = 31 - (J >> 1);
  const int par = J & 1;
  const int q0 = qt << 6;
  const int n = qt + 1;
  const int iters = (n - par + 1) >> 1;     // tiles jt = par, par+2, ...
  const int tid = threadIdx.x, w = tid >> 6, l = tid & 63;
  const int lr = l & 15, lg = l >> 4;

  const BF16* Q  = qkv + (size_t)bh * (T * 64);
  const BF16* Kp = qkv + 4194304 + (size_t)bh * (T * 64);
  const BF16* Vt = qkv + 8388608 + (size_t)bh * (64 * T);

  __shared__ __align__(16) BF16 ldsK[2][4096];
  __shared__ __align__(16) BF16 ldsV[2][4096];   // 32KB total -> 5 blocks/CU

  const float C1 = 0.18033688011112042f;   // log2(e)/8
  const float C2 = 17.312340490667562f;    // 12*log2(e)  (static max M=12)
  const int swzl = (lr & 7) << 3;          // read-side XOR (elements)

  // Q fragments for this wave's 16 rows (global, no LDS)
  short8 qf[2];
#pragma unroll
  for (int c = 0; c < 2; ++c)
    qf[c] = *(const short8*)(Q + (size_t)(q0 + w * 16 + lr) * 64 + c * 32 + lg * 8);

  floatx4 acc_o[4] = {};
  floatx4 lsum4 = {0.f, 0.f, 0.f, 0.f};

  // strength-reduced staging pointers: lane's slice for tile `par`;
  // advance K by 2 tiles (8192 elems), V by 2 tiles (128 elems) per STAGE2.
  const int t0 = w * 64 + l, t1 = t0 + 256;
  const int r0 = t0 >> 3, ch0 = (t0 & 7) ^ (r0 & 7);
  const int r1 = t1 >> 3, ch1 = (t1 & 7) ^ (r1 & 7);
  const BF16* kg0 = Kp + (((size_t)(par * 64 + r0)) << 6) + ch0 * 8;
  const BF16* kg1 = Kp + (((size_t)(par * 64 + r1)) << 6) + ch1 * 8;
  const BF16* vg0 = Vt + (size_t)r0 * T + par * 64 + ch0 * 8;
  const BF16* vg1 = Vt + (size_t)r1 * T + par * 64 + ch1 * 8;

#define STAGE2(BUF)                                           \
  {                                                           \
    gload_lds16(kg0, &ldsK[BUF][w * 512]);                    \
    gload_lds16(vg0, &ldsV[BUF][w * 512]);                    \
    gload_lds16(kg1, &ldsK[BUF][w * 512 + 2048]);             \
    gload_lds16(vg1, &ldsV[BUF][w * 512 + 2048]);             \
    kg0 += 8192; kg1 += 8192; vg0 += 128; vg1 += 128;         \
  }

#define TILE(IT, MASKED)                                                      \
  {                                                                           \
    const int cur_ = (IT) & 1;                                                \
    if ((IT) + 1 < iters) {                                                   \
      STAGE2(cur_ ^ 1);                                                       \
      asm volatile("s_waitcnt vmcnt(4)" ::: "memory");                        \
    } else {                                                                  \
      asm volatile("s_waitcnt vmcnt(0)" ::: "memory");                        \
    }                                                                         \
    __builtin_amdgcn_s_barrier();                                             \
    floatx4 accs[4] = {};                                                     \
    __builtin_amdgcn_s_setprio(1);                                            \
    _Pragma("unroll")                                                         \
    for (int c = 0; c < 2; ++c)                                               \
      _Pragma("unroll")                                                       \
      for (int n4 = 0; n4 < 4; ++n4) {                                        \
        short8 kf = *(const short8*)(&ldsK[cur_][(n4 * 16 + lr) * 64 +        \
                                                ((c * 32 + lg * 8) ^ swzl)]); \
        accs[n4] = __builtin_amdgcn_mfma_f32_16x16x32_bf16(kf, qf[c], accs[n4], 0, 0, 0); \
      }                                                                       \
    __builtin_amdgcn_s_setprio(0);                                            \
    _Pragma("unroll")                                                         \
    for (int n4 = 0; n4 < 4; ++n4)                                            \
      _Pragma("unroll")                                                       \
      for (int j = 0; j < 4; ++j) {                                           \
        float p = exp2f(fmaf(accs[n4][j], C1, -C2));                          \
        if (MASKED && (n4 * 16 + lg * 4 + j > w * 16 + lr)) p = 0.f;          \
        lsum4[j] += p;                                                        \
        accs[n4][j] = p;                                                      \
      }                                                                       \
    __builtin_amdgcn_s_setprio(1);                                            \
    _Pragma("unroll")                                                         \
    for (int c = 0; c < 2; ++c) {                                             \
      unsigned int a0 = cvt_pk_bf16(accs[2 * c][0], accs[2 * c][1]);          \
      unsigned int b0 = cvt_pk_bf16(accs[2 * c + 1][0], accs[2 * c + 1][1]);  \
      unsigned int a1 = cvt_pk_bf16(accs[2 * c][2], accs[2 * c][3]);          \
      unsigned int b1 = cvt_pk_bf16(accs[2 * c + 1][2], accs[2 * c + 1][3]);  \
      asm("v_permlane32_swap_b32 %0, %1" : "+v"(a0), "+v"(b0));               \
      asm("v_permlane32_swap_b32 %0, %1" : "+v"(a1), "+v"(b1));               \
      asm("v_permlane16_swap_b32 %0, %1" : "+v"(a0), "+v"(b0));               \
      asm("v_permlane16_swap_b32 %0, %1" : "+v"(a1), "+v"(b1));               \
      uintx4 pw; pw[0] = a0; pw[1] = a1; pw[2] = b0; pw[3] = b1;              \
      short8 pf = __builtin_bit_cast(short8, pw);                             \
      _Pragma("unroll")                                                       \
      for (int n4 = 0; n4 < 4; ++n4) {                                        \
        short8 vf = *(const short8*)(&ldsV[cur_][(n4 * 16 + lr) * 64 +        \
                                                ((c * 32 + lg * 8) ^ swzl)]); \
        acc_o[n4] = __builtin_amdgcn_mfma_f32_16x16x32_bf16(pf, vf, acc_o[n4], 0, 0, 0); \
      }                                                                       \
    }                                                                         \
    __builtin_amdgcn_s_setprio(0);                                            \
    __builtin_amdgcn_s_barrier();                                             \
  }

  // peel the diagonal tile (it is the LAST tile of the par==(qt&1) half)
  const int full = iters - ((par == (qt & 1)) ? 1 : 0);
  if (iters > 0) {
    STAGE2(0);
    for (int it = 0; it < full; ++it) TILE(it, false);
    if (full < iters) TILE(full, true);
  }
#undef TILE
#undef STAGE2

  // epilogue: write un-normalized partial O (f32) + per-row lsum
  const int slot = (bh * 32 + qt) * 2 + par;
  float lsum = (lsum4[0] + lsum4[1]) + (lsum4[2] + lsum4[3]);
  lsum += __shfl_xor(lsum, 16, 64);
  lsum += __shfl_xor(lsum, 32, 64);
  if (lg == 0) PL[slot * 64 + w * 16 + lr] = lsum;
  float* po = PO + (size_t)slot * 4096;
#pragma unroll
  for (int n4 = 0; n4 < 4; ++n4)
#pragma unroll
    for (int j = 0; j < 4; ++j)
      po[(w * 16 + lg * 4 + j) * 64 + n4 * 16 + lr] = acc_o[n4][j];
}

// ---------- merge the two KV-halves: y = (OA+OB)/(lA+lB), bf16 ----------
__global__ __launch_bounds__(256)
void attn_merge(const float* __restrict__ PO, const float* __restrict__ PL,
                BF16* __restrict__ y) {
  const int g = blockIdx.x * 256 + threadIdx.x;  // 524288 threads, 8 f32 each
  const int qi = g >> 9;                          // bh*32+qt in [0,1024)
  const int rem = (g & 511) << 3;                 // [0,4096) step 8
  const int r = rem >> 6, d0 = rem & 63;
  const float* A = PO + (size_t)qi * 8192 + rem;
  const float* B = A + 4096;
  const float lA = PL[qi * 128 + r];
  const float lB = PL[qi * 128 + 64 + r];
  const float inv = 1.0f / (lA + lB);
  float4 a0 = *(const float4*)A, a1 = *(const float4*)(A + 4);
  float4 b0 = *(const float4*)B, b1 = *(const float4*)(B + 4);
  const int bh = qi >> 5, qt = qi & 31;
  const int b = bh >> 4, h = bh & 15;
  const int t = qt * 64 + r;
  short8 v;
  v[0] = (short)f2bf((a0.x + b0.x) * inv);
  v[1] = (short)f2bf((a0.y + b0.y) * inv);
  v[2] = (short)f2bf((a0.z + b0.z) * inv);
  v[3] = (short)f2bf((a0.w + b0.w) * inv);
  v[4] = (short)f2bf((a1.x + b1.x) * inv);
  v[5] = (short)f2bf((a1.y + b1.y) * inv);
  v[6] = (short)f2bf((a1.z + b1.z) * inv);
  v[7] = (short)f2bf((a1.w + b1.w) * inv);
  *(short8*)(y + ((size_t)b * 2048 + t) * 1024 + h * 64 + d0) = v;
}

extern "C" void kernel_launch(void* const* d_in, const int* in_sizes, int n_in,
                              void* d_out, int out_size, void* d_ws, size_t ws_size,
                              hipStream_t stream) {
  const float* x      = (const float*)d_in[0];
  const float* W_attn = (const float*)d_in[1];
  const float* b_attn = (const float*)d_in[2];
  const float* W_proj = (const float*)d_in[3];
  const float* b_proj = (const float*)d_in[4];
  float* out = (float*)d_out;
  BF16* ws  = (BF16*)d_ws;

  BF16* xb      = ws;                               // [4096][1024]
  BF16* wt_attn = xb + 4194304;                     // [3072][1024]
  BF16* wt_proj = wt_attn + 3145728;                // [1024][1024]
  BF16* qkv     = wt_proj + 1048576;                // q,k,vt (12582912 elems)
  BF16* y       = qkv + 12582912;                   // [4096][1024]
  float* PO     = (float*)(y + 4194304);            // [2048][64][64] f32 partial O
  float* PL     = PO + 8388608;                     // [2048][64] f32 partial lsum

  hipLaunchKernelGGL(cvt_bf16, dim3(2048), dim3(256), 0, stream,
                     x, (unsigned short*)xb, 4194304);
  hipLaunchKernelGGL(transpose_cvt, dim3(48 * 16), dim3(256), 0, stream,
                     W_attn, (unsigned short*)wt_attn, 1024, 3072);
  hipLaunchKernelGGL(transpose_cvt, dim3(16 * 16), dim3(256), 0, stream,
                     W_proj, (unsigned short*)wt_proj, 1024, 1024);
  hipLaunchKernelGGL(gemm_qkv, dim3(256), dim3(512), 0, stream,
                     xb, wt_attn, b_attn, qkv, 4096, 3072, 1024);
  hipLaunchKernelGGL(flash_attn, dim3(2048), dim3(256), 0, stream, qkv, PO, PL);
  hipLaunchKernelGGL(attn_merge, dim3(2048), dim3(256), 0, stream, PO, PL, y);
  hipLaunchKernelGGL(gemm_proj, dim3(32 * 8), dim3(256), 0, stream,
                     y, wt_proj, b_proj, out, 4096, 1024, 1024);
}

// Round 9
// 109.574 us; speedup vs baseline: 1.1768x; 1.1768x over previous
//
#include <hip/hip_runtime.h>
#include <hip/hip_bf16.h>

typedef __attribute__((ext_vector_type(8))) short short8;
typedef __attribute__((ext_vector_type(4))) float floatx4;
typedef __attribute__((ext_vector_type(4))) unsigned int uintx4;
#define BF16 __hip_bfloat16

__device__ __forceinline__ unsigned short f2bf(float f) {
  unsigned int u = __builtin_bit_cast(unsigned int, f);
  unsigned int r = (u + 0x7FFFu + ((u >> 16) & 1u)) >> 16;
  return (unsigned short)r;
}

__device__ __forceinline__ unsigned int cvt_pk_bf16(float lo, float hi) {
  unsigned int r;
  asm("v_cvt_pk_bf16_f32 %0, %1, %2" : "=v"(r) : "v"(lo), "v"(hi));
  return r;
}

__device__ __forceinline__ void gload_lds16(const void* g, void* l) {
  __builtin_amdgcn_global_load_lds(
      (const __attribute__((address_space(1))) unsigned int*)g,
      (__attribute__((address_space(3))) unsigned int*)l, 16, 0, 0);
}

// ---------- elementwise f32 -> bf16 ----------
__global__ __launch_bounds__(256)
void cvt_bf16(const float* __restrict__ in, unsigned short* __restrict__ out, int n) {
  int i = (blockIdx.x * 256 + threadIdx.x) * 8;
  if (i >= n) return;
  float4 a = *(const float4*)(in + i);
  float4 b = *(const float4*)(in + i + 4);
  short8 v;
  v[0] = (short)f2bf(a.x); v[1] = (short)f2bf(a.y);
  v[2] = (short)f2bf(a.z); v[3] = (short)f2bf(a.w);
  v[4] = (short)f2bf(b.x); v[5] = (short)f2bf(b.y);
  v[6] = (short)f2bf(b.z); v[7] = (short)f2bf(b.w);
  *(short8*)(out + i) = v;
}

// ---------- transpose+convert: in[K][N] f32 -> out[N][K] bf16 ----------
__global__ __launch_bounds__(256)
void transpose_cvt(const float* __restrict__ in, unsigned short* __restrict__ out,
                   int K, int N) {
  __shared__ float tile[64][65];
  const int nb = N >> 6;
  const int tn = blockIdx.x % nb, tk = blockIdx.x / nb;
  const int n0 = tn << 6, k0 = tk << 6;
  const int tid = threadIdx.x;
#pragma unroll
  for (int c = 0; c < 4; ++c) {
    int t = tid + c * 256;            // [0,1024): 64 rows x 16 float4
    int r = t >> 4, col = (t & 15) << 2;
    float4 v = *(const float4*)(in + (size_t)(k0 + r) * N + n0 + col);
    tile[r][col] = v.x; tile[r][col + 1] = v.y;
    tile[r][col + 2] = v.z; tile[r][col + 3] = v.w;
  }
  __syncthreads();
#pragma unroll
  for (int c = 0; c < 2; ++c) {
    int t = tid + c * 256;            // [0,512): 64 n-rows x 8 short8
    int r = t >> 3, col = (t & 7) << 3;   // r = local n, col = local k
    short8 v;
#pragma unroll
    for (int j = 0; j < 8; ++j) v[j] = (short)f2bf(tile[col + j][r]);
    *(short8*)(out + (size_t)(n0 + r) * K + k0 + col) = v;
  }
}

// ---------- GEMM: C[M][N] = A[M][K] @ Bt[N][K]^T + bias ----------
// R2-proven config (session-best GEMM): 128x128, BK=64, single-buffered,
// 256 thr, grid 768/256 (>=3 or 1 independent blocks/CU). Six scheduling
// variants (BK32, dbuf x3, 4-phase, 256x192-1buf) all measured WORSE --
// independent small blocks hide each other's staging drains; synchronized
// big blocks don't. XOR-swizzled both-sides (0 conflicts).
// EPI 0: scatter-write qkv bf16 (q,k -> [2][16][2048][64]; v -> [2][16][64][2048])
// EPI 1: plain row-major [M][N] f32 write
template <int EPI>
__global__ __launch_bounds__(256, 2)
void gemm_bt(const BF16* __restrict__ A, const BF16* __restrict__ Bt,
             const float* __restrict__ bias, void* __restrict__ outv,
             int M, int N, int K) {
  const int tid = threadIdx.x;
  const int w = tid >> 6, l = tid & 63;
  const int lr = l & 15, lg = l >> 4;
  const int nbx = N >> 7;
  const int bm = blockIdx.x / nbx, bn = blockIdx.x % nbx;
  const int row0 = bm << 7, col0 = bn << 7;
  const int wr = (w >> 1) << 6, wc = (w & 1) << 6;

  __shared__ __align__(16) BF16 ldsA[128 * 64];
  __shared__ __align__(16) BF16 ldsB[128 * 64];

  floatx4 acc[4][4] = {};
  const int swzl = (lr & 7) << 3;   // read-side XOR (elements); row&7 == lr&7

  for (int k0 = 0; k0 < K; k0 += 64) {
#pragma unroll
    for (int c = 0; c < 4; ++c) {
      int t = w * 64 + l + c * 256;        // [0,1024): 128 rows x 8 chunks(16B)
      int ar = t >> 3;
      int ch = (t & 7) ^ (ar & 7);         // pre-swizzled source chunk
      gload_lds16(A + (size_t)(row0 + ar) * K + k0 + (ch << 3),
                  ldsA + w * 512 + c * 2048);
      gload_lds16(Bt + (size_t)(col0 + ar) * K + k0 + (ch << 3),
                  ldsB + w * 512 + c * 2048);
    }
    __syncthreads();
#pragma unroll
    for (int kk = 0; kk < 64; kk += 32) {
      short8 af[4], bf[4];
#pragma unroll
      for (int m = 0; m < 4; ++m)
        af[m] = *(const short8*)(ldsA + (wr + m * 16 + lr) * 64 + ((kk + lg * 8) ^ swzl));
#pragma unroll
      for (int n = 0; n < 4; ++n)
        bf[n] = *(const short8*)(ldsB + (wc + n * 16 + lr) * 64 + ((kk + lg * 8) ^ swzl));
#pragma unroll
      for (int m = 0; m < 4; ++m)
#pragma unroll
        for (int n = 0; n < 4; ++n)
          acc[m][n] = __builtin_amdgcn_mfma_f32_16x16x32_bf16(af[m], bf[n], acc[m][n], 0, 0, 0);
    }
    __syncthreads();
  }

#pragma unroll
  for (int m = 0; m < 4; ++m)
#pragma unroll
    for (int n = 0; n < 4; ++n)
#pragma unroll
      for (int j = 0; j < 4; ++j) {
        int row = row0 + wr + m * 16 + lg * 4 + j;   // m index (b*2048 + t)
        int col = col0 + wc + n * 16 + lr;           // n index
        float v = acc[m][n][j] + bias[col];
        if (EPI == 0) {
          BF16* out = (BF16*)outv;
          int s = col >> 10, cc = col & 1023;
          int hh = cc >> 6, dd = cc & 63;
          int bb = row >> 11, tt = row & 2047;
          size_t addr;
          if (s == 2)
            addr = (size_t)8388608 + (((size_t)bb * 16 + hh) * 64 + dd) * 2048 + tt;
          else
            addr = (size_t)s * 4194304 + (((size_t)bb * 16 + hh) * 2048 + tt) * 64 + dd;
          out[addr] = __float2bfloat16(v);
        } else {
          float* out = (float*)outv;
          out[(size_t)row * N + col] = v;
        }
      }
}

// ---------- causal flash attention ----------
// q: [2][16][2048][64], k: [2][16][2048][64], vt: [2][16][64][2048]
// y: [2][2048][1024] bf16  (= [B][T][H*D])
// R9 = R2 session-best structure (1024 blocks x 256 thr, balanced long/short
// q-tile pairing, dbuf K/V with counted vmcnt(4), swapped QK^T + in-register
// P via cvt_pk+permlane, static-max softmax) + R4-proven VALU diet:
//  * diag-peel: main loop unmasked, single masked tile at the end
//  * strength-reduced staging pointers (+= const per tile)
//  * lsum as 4 independent chains (breaks 16-deep serial add)
__global__ __launch_bounds__(256, 4)
void flash_attn(const BF16* __restrict__ qkv, BF16* __restrict__ y) {
  const int T = 2048;
  const int i = blockIdx.x;
  const int xcd = i & 7, s = i >> 3;          // blocks round-robin XCDs
  // parity alternates under both consecutive (s&1) and stride-32 ((s>>5)&1)
  const int par = (s ^ (s >> 5)) & 1;
  const int rnk = ((s >> 5) << 4) | ((s & 31) >> 1);   // [0,64)
  const int bh = xcd * 4 + (rnk & 3);         // 4 heads per XCD -> 2MB L2 set
  const int hq = rnk >> 2;                    // [0,16)
  const int qt = par ? hq : (31 - hq);        // pair (31-h, h): 33 tiles/pair
  const int b = bh >> 4, h = bh & 15;
  const int q0 = qt << 6;
  const int tid = threadIdx.x, w = tid >> 6, l = tid & 63;
  const int lr = l & 15, lg = l >> 4;

  const BF16* Q  = qkv + (size_t)bh * T * 64;
  const BF16* Kp = qkv + 4194304 + (size_t)bh * T * 64;
  const BF16* Vt = qkv + 8388608 + (size_t)bh * 64 * T;

  __shared__ __align__(16) BF16 ldsK[2][4096];
  __shared__ __align__(16) BF16 ldsV[2][6144];   // padded: LDS stays 40960 B

  const float C1 = 0.18033688011112042f;   // log2(e)/8
  const float C2 = 17.312340490667562f;    // 12*log2(e)  (static max M=12)
  const int swzl = (lr & 7) << 3;          // read-side XOR (elements)
  const int nt = qt + 1;

  // Q fragments for this wave's 16 rows (global, no LDS)
  short8 qf[2];
#pragma unroll
  for (int c = 0; c < 2; ++c)
    qf[c] = *(const short8*)(Q + (size_t)(q0 + w * 16 + lr) * 64 + c * 32 + lg * 8);

  floatx4 acc_o[4] = {};
  floatx4 lsum4 = {0.f, 0.f, 0.f, 0.f};

  // strength-reduced staging pointers (lane slice of tile 0); per-tile step:
  // K rows advance 64*64 elems, Vt cols advance 64 elems.
  const int t0 = w * 64 + l, t1 = t0 + 256;
  const int r0 = t0 >> 3, ch0 = (t0 & 7) ^ (r0 & 7);
  const int r1 = t1 >> 3, ch1 = (t1 & 7) ^ (r1 & 7);
  const BF16* kg0 = Kp + ((size_t)r0 << 6) + ch0 * 8;
  const BF16* kg1 = Kp + ((size_t)r1 << 6) + ch1 * 8;
  const BF16* vg0 = Vt + (size_t)r0 * T + ch0 * 8;
  const BF16* vg1 = Vt + (size_t)r1 * T + ch1 * 8;

#define STAGE2(BUF)                                           \
  {                                                           \
    gload_lds16(kg0, &ldsK[BUF][w * 512]);                    \
    gload_lds16(vg0, &ldsV[BUF][w * 512]);                    \
    gload_lds16(kg1, &ldsK[BUF][w * 512 + 2048]);             \
    gload_lds16(vg1, &ldsV[BUF][w * 512 + 2048]);             \
    kg0 += 4096; kg1 += 4096; vg0 += 64; vg1 += 64;           \
  }

#define TILE(IT, MASKED)                                                      \
  {                                                                           \
    const int cur_ = (IT) & 1;                                                \
    if ((IT) + 1 < nt) {                                                      \
      STAGE2(cur_ ^ 1);                                                       \
      asm volatile("s_waitcnt vmcnt(4)" ::: "memory");   /* tile IT landed */ \
    } else {                                                                  \
      asm volatile("s_waitcnt vmcnt(0)" ::: "memory");                        \
    }                                                                         \
    __builtin_amdgcn_s_barrier();                                             \
    /* S^T = K @ Q^T: lane holds S[q=lr][key = n4*16+lg*4+j] */               \
    floatx4 accs[4] = {};                                                     \
    __builtin_amdgcn_s_setprio(1);                                            \
    _Pragma("unroll")                                                         \
    for (int c = 0; c < 2; ++c)                                               \
      _Pragma("unroll")                                                       \
      for (int n4 = 0; n4 < 4; ++n4) {                                        \
        short8 kf = *(const short8*)(&ldsK[cur_][(n4 * 16 + lr) * 64 +        \
                                                ((c * 32 + lg * 8) ^ swzl)]); \
        accs[n4] = __builtin_amdgcn_mfma_f32_16x16x32_bf16(kf, qf[c], accs[n4], 0, 0, 0); \
      }                                                                       \
    __builtin_amdgcn_s_setprio(0);                                            \
    /* static-max softmax in-register */                                      \
    _Pragma("unroll")                                                         \
    for (int n4 = 0; n4 < 4; ++n4)                                            \
      _Pragma("unroll")                                                       \
      for (int j = 0; j < 4; ++j) {                                           \
        float p = exp2f(fmaf(accs[n4][j], C1, -C2));                          \
        if (MASKED && (n4 * 16 + lg * 4 + j > w * 16 + lr)) p = 0.f;          \
        lsum4[j] += p;                                                        \
        accs[n4][j] = p;                                                      \
      }                                                                       \
    /* O += P @ V ; P-fragments in-register (cvt_pk + permlane swaps) */      \
    __builtin_amdgcn_s_setprio(1);                                            \
    _Pragma("unroll")                                                         \
    for (int c = 0; c < 2; ++c) {                                             \
      unsigned int a0 = cvt_pk_bf16(accs[2 * c][0], accs[2 * c][1]);          \
      unsigned int b0 = cvt_pk_bf16(accs[2 * c + 1][0], accs[2 * c + 1][1]);  \
      unsigned int a1 = cvt_pk_bf16(accs[2 * c][2], accs[2 * c][3]);          \
      unsigned int b1 = cvt_pk_bf16(accs[2 * c + 1][2], accs[2 * c + 1][3]);  \
      asm("v_permlane32_swap_b32 %0, %1" : "+v"(a0), "+v"(b0));               \
      asm("v_permlane32_swap_b32 %0, %1" : "+v"(a1), "+v"(b1));               \
      asm("v_permlane16_swap_b32 %0, %1" : "+v"(a0), "+v"(b0));               \
      asm("v_permlane16_swap_b32 %0, %1" : "+v"(a1), "+v"(b1));               \
      uintx4 pw; pw[0] = a0; pw[1] = a1; pw[2] = b0; pw[3] = b1;              \
      short8 pf = __builtin_bit_cast(short8, pw);                             \
      _Pragma("unroll")                                                       \
      for (int n4 = 0; n4 < 4; ++n4) {                                        \
        short8 vf = *(const short8*)(&ldsV[cur_][(n4 * 16 + lr) * 64 +        \
                                                ((c * 32 + lg * 8) ^ swzl)]); \
        acc_o[n4] = __builtin_amdgcn_mfma_f32_16x16x32_bf16(pf, vf, acc_o[n4], 0, 0, 0); \
      }                                                                       \
    }                                                                         \
    __builtin_amdgcn_s_setprio(0);                                            \
    __builtin_amdgcn_s_barrier();                                             \
  }

  STAGE2(0);
  for (int it = 0; it < nt - 1; ++it) TILE(it, false);
  TILE(nt - 1, true);    // diagonal tile is always the last
#undef TILE
#undef STAGE2

  // reduce lsum across the 4 lg-groups of each q-row (lr), normalize, write
  float lsum = (lsum4[0] + lsum4[1]) + (lsum4[2] + lsum4[3]);
  lsum += __shfl_xor(lsum, 16, 64);
  lsum += __shfl_xor(lsum, 32, 64);
  float inv_own = 1.0f / lsum;
  float inv[4];
#pragma unroll
  for (int j = 0; j < 4; ++j) inv[j] = __shfl(inv_own, lg * 4 + j, 64);
#pragma unroll
  for (int n4 = 0; n4 < 4; ++n4)
#pragma unroll
    for (int j = 0; j < 4; ++j) {
      int qr = q0 + w * 16 + lg * 4 + j;
      int dd = n4 * 16 + lr;
      y[((size_t)b * 2048 + qr) * 1024 + h * 64 + dd] =
          __float2bfloat16(acc_o[n4][j] * inv[j]);
    }
}

extern "C" void kernel_launch(void* const* d_in, const int* in_sizes, int n_in,
                              void* d_out, int out_size, void* d_ws, size_t ws_size,
                              hipStream_t stream) {
  const float* x      = (const float*)d_in[0];
  const float* W_attn = (const float*)d_in[1];
  const float* b_attn = (const float*)d_in[2];
  const float* W_proj = (const float*)d_in[3];
  const float* b_proj = (const float*)d_in[4];
  float* out = (float*)d_out;
  BF16* ws  = (BF16*)d_ws;

  BF16* xb      = ws;                               // [4096][1024]
  BF16* wt_attn = xb + 4194304;                     // [3072][1024]
  BF16* wt_proj = wt_attn + 3145728;                // [1024][1024]
  BF16* qkv     = wt_proj + 1048576;                // q,k,vt (12582912 elems)
  BF16* y       = qkv + 12582912;                   // [4096][1024]

  hipLaunchKernelGGL(cvt_bf16, dim3(2048), dim3(256), 0, stream,
                     x, (unsigned short*)xb, 4194304);
  hipLaunchKernelGGL(transpose_cvt, dim3(48 * 16), dim3(256), 0, stream,
                     W_attn, (unsigned short*)wt_attn, 1024, 3072);
  hipLaunchKernelGGL(transpose_cvt, dim3(16 * 16), dim3(256), 0, stream,
                     W_proj, (unsigned short*)wt_proj, 1024, 1024);
  hipLaunchKernelGGL(gemm_bt<0>, dim3(32 * 24), dim3(256), 0, stream,
                     xb, wt_attn, b_attn, (void*)qkv, 4096, 3072, 1024);
  hipLaunchKernelGGL(flash_attn, dim3(1024), dim3(256), 0, stream, qkv, y);
  hipLaunchKernelGGL(gemm_bt<1>, dim3(32 * 8), dim3(256), 0, stream,
                     y, wt_proj, b_proj, (void*)out, 4096, 1024, 1024);
}